// Round 1
// baseline (319.722 us; speedup 1.0000x reference)
//
#include <hip/hip_runtime.h>

typedef __attribute__((ext_vector_type(8))) _Float16 half8;
typedef __attribute__((ext_vector_type(4))) _Float16 half4;
typedef __attribute__((ext_vector_type(2))) _Float16 half2v;
typedef __attribute__((ext_vector_type(4))) float f32x4;
typedef __attribute__((ext_vector_type(4))) int i32x4;

typedef __attribute__((address_space(1))) void* gptr_t;
typedef __attribute__((address_space(3))) void* lptr_t;
#define GLL16(g, l) __builtin_amdgcn_global_load_lds((gptr_t)(g), (lptr_t)(l), 16, 0, 0)

// ---------------- prep kernels ----------------

__global__ void cvt_x_kernel(const float* __restrict__ x, _Float16* __restrict__ xh) {
  size_t i = (size_t)blockIdx.x * blockDim.x + threadIdx.x;
  float4 v = *reinterpret_cast<const float4*>(x + i * 4);
  half4 o = { (_Float16)v.x, (_Float16)v.y, (_Float16)v.z, (_Float16)v.w };
  *reinterpret_cast<half4*>(xh + i * 4) = o;
}

// w [1024][N] fp32 -> wt [N][1024] fp16 (K-contiguous)
__global__ void transpose_cvt_kernel(const float* __restrict__ w, _Float16* __restrict__ wt, int N) {
  int tid = blockIdx.x * blockDim.x + threadIdx.x;
  int n = tid % N, kc = tid / N;
  half8 o;
#pragma unroll
  for (int i = 0; i < 8; ++i) o[i] = (_Float16)w[(size_t)(kc * 8 + i) * N + n];
  *reinterpret_cast<half8*>(wt + (size_t)n * 1024 + kc * 8) = o;
}

// ---------------- fp16 GEMM, 128x128 tile, BK=64, K=1024 ----------------
// EPI=0: qkv projection epilogue (bias, split q/k/v, q scaled, v transposed)
// EPI=1: output projection epilogue (bias, fp32 store)

template<int EPI>
__global__ __launch_bounds__(256, 2)
void gemm16(const _Float16* __restrict__ A, const _Float16* __restrict__ Bt,
            const float* __restrict__ bias,
            _Float16* __restrict__ qh, _Float16* __restrict__ kh,
            _Float16* __restrict__ vT, float* __restrict__ outf) {
  __shared__ __align__(16) _Float16 Ah[128 * 64];
  __shared__ __align__(16) _Float16 Bh[128 * 64];
  const int t = threadIdx.x;
  const int w = t >> 6, ln = t & 63, G = ln >> 4, c = ln & 15;
  const int m0 = blockIdx.y * 128, n0 = blockIdx.x * 128;
  const int wr = w >> 1, wc = w & 1;
  f32x4 acc[4][4] = {};
  for (int kt = 0; kt < 1024; kt += 64) {
    // stage A,B tiles: linear LDS dest, XOR-pre-swizzled global source (rule #21)
#pragma unroll
    for (int i = 0; i < 4; ++i) {
      int ch = i * 256 + t;
      int row = ch >> 3, kc = ch & 7;
      int kk = kt + ((kc ^ (row & 7)) << 3);
      int ldsbase = (i * 256 + w * 64) * 8; // halves; wave-uniform base
      GLL16(A + (size_t)(m0 + row) * 1024 + kk, Ah + ldsbase);
      GLL16(Bt + (size_t)(n0 + row) * 1024 + kk, Bh + ldsbase);
    }
    __syncthreads();
    half8 aF[2][4], bF[2][4];
#pragma unroll
    for (int ks = 0; ks < 2; ++ks)
#pragma unroll
      for (int i = 0; i < 4; ++i) {
        int ra = wr * 64 + i * 16 + c;
        aF[ks][i] = *reinterpret_cast<const half8*>(&Ah[ra * 64 + (((ks * 4 + G) ^ (ra & 7)) << 3)]);
        int rb = wc * 64 + i * 16 + c;
        bF[ks][i] = *reinterpret_cast<const half8*>(&Bh[rb * 64 + (((ks * 4 + G) ^ (rb & 7)) << 3)]);
      }
#pragma unroll
    for (int ks = 0; ks < 2; ++ks)
#pragma unroll
      for (int mi = 0; mi < 4; ++mi)
#pragma unroll
        for (int ni = 0; ni < 4; ++ni)
          acc[mi][ni] = __builtin_amdgcn_mfma_f32_16x16x32_f16(aF[ks][mi], bF[ks][ni], acc[mi][ni], 0, 0, 0);
    __syncthreads();
  }
  const int mbase = m0 + wr * 64, nbase = n0 + wc * 64;
#pragma unroll
  for (int ni = 0; ni < 4; ++ni) {
    int n = nbase + ni * 16 + c;
    float bv = bias[n];
    if (EPI == 0) {
      int h = n / 192;
      int rem = n - h * 192;
      int tt = rem >> 6, d = rem & 63;
#pragma unroll
      for (int mi = 0; mi < 4; ++mi)
#pragma unroll
        for (int r = 0; r < 4; ++r) {
          int m = mbase + mi * 16 + 4 * G + r;
          int bb = m >> 11, s = m & 2047;
          float val = acc[mi][ni][r] + bv;
          size_t bh = (size_t)(bb * 16 + h);
          if (tt == 0)      qh[(bh * 2048 + s) * 64 + d] = (_Float16)(val * 0.125f);
          else if (tt == 1) kh[(bh * 2048 + s) * 64 + d] = (_Float16)val;
          else              vT[(bh * 64 + d) * 2048 + s] = (_Float16)val;
        }
    } else {
#pragma unroll
      for (int mi = 0; mi < 4; ++mi)
#pragma unroll
        for (int r = 0; r < 4; ++r) {
          int m = mbase + mi * 16 + 4 * G + r;
          outf[(size_t)m * 1024 + n] = acc[mi][ni][r] + bv;
        }
    }
  }
}

// ---------------- flash attention: 1 wave = 16 q rows, swapped QK^T ----------------

__global__ __launch_bounds__(256, 2)
void attn_kernel(const _Float16* __restrict__ qh, const _Float16* __restrict__ kh,
                 const _Float16* __restrict__ vT, _Float16* __restrict__ ao) {
  const int t = threadIdx.x;
  const int w = t >> 6, ln = t & 63, G = ln >> 4, c = ln & 15;
  const int bh = blockIdx.y;
  const int q0 = blockIdx.x * 64 + w * 16;
  const _Float16* qp = qh + (size_t)bh * 2048 * 64;
  const _Float16* kp = kh + (size_t)bh * 2048 * 64;
  const _Float16* vp = vT + (size_t)bh * 64 * 2048;
  half8 qf[2];
#pragma unroll
  for (int ks = 0; ks < 2; ++ks)
    qf[ks] = *reinterpret_cast<const half8*>(qp + (size_t)(q0 + c) * 64 + ks * 32 + G * 8);
  f32x4 O[4] = {};
  float mrun = -INFINITY, lsum = 0.f;
  const bool sel_hi = (G >= 2);
  const int la = c + ((G & 1) ? 32 : 0);
  const int lb = la + 16;
  for (int jt = 0; jt < 2048; jt += 64) {
    f32x4 st[4] = {};
#pragma unroll
    for (int jf = 0; jf < 4; ++jf)
#pragma unroll
      for (int ks = 0; ks < 2; ++ks) {
        half8 kf = *reinterpret_cast<const half8*>(kp + (size_t)(jt + jf * 16 + c) * 64 + ks * 32 + G * 8);
        st[jf] = __builtin_amdgcn_mfma_f32_16x16x32_f16(kf, qf[ks], st[jf], 0, 0, 0);
      }
    // online softmax (state indexed by q = c, uniform across G after xor-reduce)
    float tm = -INFINITY;
#pragma unroll
    for (int jf = 0; jf < 4; ++jf)
#pragma unroll
      for (int r = 0; r < 4; ++r) tm = fmaxf(tm, st[jf][r]);
    tm = fmaxf(tm, __shfl_xor(tm, 16));
    tm = fmaxf(tm, __shfl_xor(tm, 32));
    float mnew = fmaxf(mrun, tm);
    float corr = __expf(mrun - mnew);
    float ps = 0.f;
    unsigned up[4][2];
#pragma unroll
    for (int jf = 0; jf < 4; ++jf) {
      float p0 = __expf(st[jf][0] - mnew), p1 = __expf(st[jf][1] - mnew);
      float p2 = __expf(st[jf][2] - mnew), p3 = __expf(st[jf][3] - mnew);
      ps += (p0 + p1) + (p2 + p3);
      half2v h01 = { (_Float16)p0, (_Float16)p1 };
      half2v h23 = { (_Float16)p2, (_Float16)p3 };
      up[jf][0] = __builtin_bit_cast(unsigned, h01);
      up[jf][1] = __builtin_bit_cast(unsigned, h23);
    }
    ps += __shfl_xor(ps, 16);
    ps += __shfl_xor(ps, 32);
    lsum = lsum * corr + ps;
    mrun = mnew;
#pragma unroll
    for (int df = 0; df < 4; ++df)
#pragma unroll
      for (int r = 0; r < 4; ++r) O[df][r] *= corr;
    // P redistribution: dest lane l elem e needs P[q=c][j=32kg+8G+e]
#pragma unroll
    for (int kg = 0; kg < 2; ++kg) {
      int f0 = 2 * kg, f1 = f0 + 1;
      int a00 = __shfl((int)up[f0][0], la); int a01 = __shfl((int)up[f0][1], la);
      int a10 = __shfl((int)up[f1][0], la); int a11 = __shfl((int)up[f1][1], la);
      int b00 = __shfl((int)up[f0][0], lb); int b01 = __shfl((int)up[f0][1], lb);
      int b10 = __shfl((int)up[f1][0], lb); int b11 = __shfl((int)up[f1][1], lb);
      i32x4 pi = { sel_hi ? a10 : a00, sel_hi ? a11 : a01,
                   sel_hi ? b10 : b00, sel_hi ? b11 : b01 };
      half8 pf = __builtin_bit_cast(half8, pi);
#pragma unroll
      for (int df = 0; df < 4; ++df) {
        half8 vf = *reinterpret_cast<const half8*>(vp + (size_t)(df * 16 + c) * 2048 + jt + kg * 32 + G * 8);
        O[df] = __builtin_amdgcn_mfma_f32_16x16x32_f16(vf, pf, O[df], 0, 0, 0);
      }
    }
  }
  float inv = 1.f / lsum;
  const int bb = bh >> 4, h = bh & 15;
  const size_t srow = (size_t)bb * 2048 + q0 + c;
#pragma unroll
  for (int df = 0; df < 4; ++df) {
    half4 o = { (_Float16)(O[df][0] * inv), (_Float16)(O[df][1] * inv),
                (_Float16)(O[df][2] * inv), (_Float16)(O[df][3] * inv) };
    *reinterpret_cast<half4*>(ao + srow * 1024 + h * 64 + df * 16 + 4 * G) = o;
  }
}

// ---------------- launch ----------------

extern "C" void kernel_launch(void* const* d_in, const int* in_sizes, int n_in,
                              void* d_out, int out_size, void* d_ws, size_t ws_size,
                              hipStream_t stream) {
  const float* x     = (const float*)d_in[0];
  const float* w_qkv = (const float*)d_in[1];
  const float* b_qkv = (const float*)d_in[2];
  const float* w_o   = (const float*)d_in[3];
  const float* b_o   = (const float*)d_in[4];
  float* out = (float*)d_out;
  char* ws = (char*)d_ws;
  _Float16* xh    = (_Float16*)(ws);                       // 8 MB  [4096][1024]
  _Float16* wqkvT = (_Float16*)(ws + ((size_t)8  << 20));  // 6 MB  [3072][1024]
  _Float16* woT   = (_Float16*)(ws + ((size_t)14 << 20));  // 2 MB  [1024][1024]
  _Float16* qh    = (_Float16*)(ws + ((size_t)16 << 20));  // 8 MB  [32][2048][64] (pre-scaled)
  _Float16* kh    = (_Float16*)(ws + ((size_t)24 << 20));  // 8 MB  [32][2048][64]
  _Float16* vT    = (_Float16*)(ws + ((size_t)32 << 20));  // 8 MB  [32][64][2048]
  _Float16* ao    = (_Float16*)(ws + ((size_t)40 << 20));  // 8 MB  [4096][1024]

  cvt_x_kernel<<<4096, 256, 0, stream>>>(x, xh);
  transpose_cvt_kernel<<<1536, 256, 0, stream>>>(w_qkv, wqkvT, 3072);
  transpose_cvt_kernel<<<512, 256, 0, stream>>>(w_o, woT, 1024);
  gemm16<0><<<dim3(24, 32), 256, 0, stream>>>(xh, wqkvT, b_qkv, qh, kh, vT, nullptr);
  attn_kernel<<<dim3(32, 32), 256, 0, stream>>>(qh, kh, vT, ao);
  gemm16<1><<<dim3(8, 32), 256, 0, stream>>>(ao, woT, b_o, nullptr, nullptr, nullptr, out);
}

// Round 2
// 158.729 us; speedup vs baseline: 2.0143x; 2.0143x over previous
//
#include <hip/hip_runtime.h>

typedef __attribute__((ext_vector_type(8))) _Float16 half8;
typedef __attribute__((ext_vector_type(4))) _Float16 half4;
typedef __attribute__((ext_vector_type(2))) _Float16 half2v;
typedef __attribute__((ext_vector_type(4))) float f32x4;
typedef __attribute__((ext_vector_type(4))) int i32x4;

typedef __attribute__((address_space(1))) void* gptr_t;
typedef __attribute__((address_space(3))) void* lptr_t;
#define GLL16(g, l) __builtin_amdgcn_global_load_lds((gptr_t)(g), (lptr_t)(l), 16, 0, 0)

__device__ __forceinline__ float fast_exp2(float x) {
  float r;
  asm volatile("v_exp_f32 %0, %1" : "=v"(r) : "v"(x));  // gfx9 VALU is interlocked; 2^x
  return r;
}

// ---------------- prep kernels ----------------

__global__ void cvt_x_kernel(const float* __restrict__ x, _Float16* __restrict__ xh) {
  size_t i = (size_t)blockIdx.x * blockDim.x + threadIdx.x;
  float4 v = *reinterpret_cast<const float4*>(x + i * 4);
  half4 o = { (_Float16)v.x, (_Float16)v.y, (_Float16)v.z, (_Float16)v.w };
  *reinterpret_cast<half4*>(xh + i * 4) = o;
}

// w [1024][N] fp32 -> wt [N][1024] fp16 (K-contiguous)
__global__ void transpose_cvt_kernel(const float* __restrict__ w, _Float16* __restrict__ wt, int N) {
  int tid = blockIdx.x * blockDim.x + threadIdx.x;
  int n = tid % N, kc = tid / N;
  half8 o;
#pragma unroll
  for (int i = 0; i < 8; ++i) o[i] = (_Float16)w[(size_t)(kc * 8 + i) * N + n];
  *reinterpret_cast<half8*>(wt + (size_t)n * 1024 + kc * 8) = o;
}

// ---------------- fp16 GEMM, 128x128 tile, BK=64, K=1024 ----------------

template<int EPI>
__global__ __launch_bounds__(256, 2)
void gemm16(const _Float16* __restrict__ A, const _Float16* __restrict__ Bt,
            const float* __restrict__ bias,
            _Float16* __restrict__ qh, _Float16* __restrict__ kh,
            _Float16* __restrict__ vT, float* __restrict__ outf) {
  __shared__ __align__(16) _Float16 Ah[128 * 64];
  __shared__ __align__(16) _Float16 Bh[128 * 64];
  const int t = threadIdx.x;
  const int w = t >> 6, ln = t & 63, G = ln >> 4, c = ln & 15;
  const int m0 = blockIdx.y * 128, n0 = blockIdx.x * 128;
  const int wr = w >> 1, wc = w & 1;
  f32x4 acc[4][4] = {};
  for (int kt = 0; kt < 1024; kt += 64) {
#pragma unroll
    for (int i = 0; i < 4; ++i) {
      int ch = i * 256 + t;
      int row = ch >> 3, kc = ch & 7;
      int kk = kt + ((kc ^ (row & 7)) << 3);
      int ldsbase = (i * 256 + w * 64) * 8;
      GLL16(A + (size_t)(m0 + row) * 1024 + kk, Ah + ldsbase);
      GLL16(Bt + (size_t)(n0 + row) * 1024 + kk, Bh + ldsbase);
    }
    __syncthreads();
    half8 aF[2][4], bF[2][4];
#pragma unroll
    for (int ks = 0; ks < 2; ++ks)
#pragma unroll
      for (int i = 0; i < 4; ++i) {
        int ra = wr * 64 + i * 16 + c;
        aF[ks][i] = *reinterpret_cast<const half8*>(&Ah[ra * 64 + (((ks * 4 + G) ^ (ra & 7)) << 3)]);
        int rb = wc * 64 + i * 16 + c;
        bF[ks][i] = *reinterpret_cast<const half8*>(&Bh[rb * 64 + (((ks * 4 + G) ^ (rb & 7)) << 3)]);
      }
#pragma unroll
    for (int ks = 0; ks < 2; ++ks)
#pragma unroll
      for (int mi = 0; mi < 4; ++mi)
#pragma unroll
        for (int ni = 0; ni < 4; ++ni)
          acc[mi][ni] = __builtin_amdgcn_mfma_f32_16x16x32_f16(aF[ks][mi], bF[ks][ni], acc[mi][ni], 0, 0, 0);
    __syncthreads();
  }
  const int mbase = m0 + wr * 64, nbase = n0 + wc * 64;
#pragma unroll
  for (int ni = 0; ni < 4; ++ni) {
    int n = nbase + ni * 16 + c;
    float bv = bias[n];
    if (EPI == 0) {
      int h = n / 192;
      int rem = n - h * 192;
      int tt = rem >> 6, d = rem & 63;
#pragma unroll
      for (int mi = 0; mi < 4; ++mi)
#pragma unroll
        for (int r = 0; r < 4; ++r) {
          int m = mbase + mi * 16 + 4 * G + r;
          int bb = m >> 11, s = m & 2047;
          float val = acc[mi][ni][r] + bv;
          size_t bh = (size_t)(bb * 16 + h);
          // q pre-scaled by hd^-0.5 * log2(e) so attn softmax runs in exp2 domain
          if (tt == 0)      qh[(bh * 2048 + s) * 64 + d] = (_Float16)(val * (0.125f * 1.44269504089f));
          else if (tt == 1) kh[(bh * 2048 + s) * 64 + d] = (_Float16)val;
          else              vT[(bh * 64 + d) * 2048 + s] = (_Float16)val;
        }
    } else {
#pragma unroll
      for (int mi = 0; mi < 4; ++mi)
#pragma unroll
        for (int r = 0; r < 4; ++r) {
          int m = mbase + mi * 16 + 4 * G + r;
          outf[(size_t)m * 1024 + n] = acc[mi][ni][r] + bv;
        }
    }
  }
}

// ---------------- flash attention v2 ----------------
// 4 waves/block, 32 q-rows/wave (2 frags), KV tile = 64 keys double-buffered in LDS.
// XCD-clustered bh mapping; swapped QK^T; exp2-domain online softmax with defer-max.

__global__ __launch_bounds__(256, 2)
void attn_kernel(const _Float16* __restrict__ qh, const _Float16* __restrict__ kh,
                 const _Float16* __restrict__ vT, _Float16* __restrict__ ao) {
  __shared__ __align__(16) _Float16 Kt[2][64 * 64];
  __shared__ __align__(16) _Float16 Vt[2][64 * 64];
  const int t = threadIdx.x;
  const int w = t >> 6, ln = t & 63, G = ln >> 4, c = ln & 15;
  // XCD-aware mapping: assume block n -> XCD n%8; give each XCD 4 contiguous bh
  const int bid = blockIdx.x;
  const int xcd = bid & 7, tt = bid >> 3;
  const int bh = xcd * 4 + (tt >> 4);
  const int qb = tt & 15;
  const int q0 = qb * 128 + w * 32;
  const _Float16* qp = qh + (size_t)bh * 2048 * 64;
  const _Float16* kp = kh + (size_t)bh * 2048 * 64;
  const _Float16* vp = vT + (size_t)bh * 64 * 2048;

  half8 qf[2][2];
#pragma unroll
  for (int f = 0; f < 2; ++f)
#pragma unroll
    for (int ks = 0; ks < 2; ++ks)
      qf[f][ks] = *reinterpret_cast<const half8*>(qp + (size_t)(q0 + f * 16 + c) * 64 + ks * 32 + G * 8);

  f32x4 O[2][4] = {};
  float mrun[2] = { -INFINITY, -INFINITY };
  float lsum[2] = { 0.f, 0.f };
  const bool sel_hi = (G >= 2);
  const int la = c + ((G & 1) ? 32 : 0);
  const int lb = la + 16;

  // staging: 512 chunks of 16B per tensor per tile; linear LDS dest, XOR-swizzled source
  auto stage = [&](int b, int jt) {
#pragma unroll
    for (int i = 0; i < 2; ++i) {
      int ch = i * 256 + t;
      int row = ch >> 3, cc = ch & 7;
      int sw = ((cc ^ (row & 7)) << 3);
      int ldsbase = (i * 256 + w * 64) * 8;
      GLL16(kp + (size_t)(jt + row) * 64 + sw, &Kt[b][ldsbase]);
      GLL16(vp + (size_t)row * 2048 + jt + sw, &Vt[b][ldsbase]);
    }
  };

  stage(0, 0);
  __syncthreads();

  for (int it = 0; it < 32; ++it) {
    const int buf = it & 1;
    if (it < 31) stage(buf ^ 1, (it + 1) * 64);

    // K fragments (shared across both q-frags)
    half8 kf[4][2];
#pragma unroll
    for (int jf = 0; jf < 4; ++jf)
#pragma unroll
      for (int ks = 0; ks < 2; ++ks)
        kf[jf][ks] = *reinterpret_cast<const half8*>(
            &Kt[buf][(jf * 16 + c) * 64 + (((ks * 4 + G) ^ (c & 7)) << 3)]);

    f32x4 st[2][4] = {};
    __builtin_amdgcn_s_setprio(1);
#pragma unroll
    for (int f = 0; f < 2; ++f)
#pragma unroll
      for (int jf = 0; jf < 4; ++jf)
#pragma unroll
        for (int ks = 0; ks < 2; ++ks)
          st[f][jf] = __builtin_amdgcn_mfma_f32_16x16x32_f16(kf[jf][ks], qf[f][ks], st[f][jf], 0, 0, 0);
    __builtin_amdgcn_s_setprio(0);

    unsigned up[2][4][2];
#pragma unroll
    for (int f = 0; f < 2; ++f) {
      float tm = -INFINITY;
#pragma unroll
      for (int jf = 0; jf < 4; ++jf)
#pragma unroll
        for (int r = 0; r < 4; ++r) tm = fmaxf(tm, st[f][jf][r]);
      tm = fmaxf(tm, __shfl_xor(tm, 16));
      tm = fmaxf(tm, __shfl_xor(tm, 32));
      // defer-max (T13): only rescale when max grew by >8 (2^8 headroom in fp16 P)
      if (!__all(tm <= mrun[f] + 8.f)) {
        float mnew = fmaxf(mrun[f], tm);
        float corr = fast_exp2(mrun[f] - mnew);
        lsum[f] *= corr;
#pragma unroll
        for (int df = 0; df < 4; ++df)
#pragma unroll
          for (int r = 0; r < 4; ++r) O[f][df][r] *= corr;
        mrun[f] = mnew;
      }
      float ps = 0.f;
#pragma unroll
      for (int jf = 0; jf < 4; ++jf) {
        float p0 = fast_exp2(st[f][jf][0] - mrun[f]);
        float p1 = fast_exp2(st[f][jf][1] - mrun[f]);
        float p2 = fast_exp2(st[f][jf][2] - mrun[f]);
        float p3 = fast_exp2(st[f][jf][3] - mrun[f]);
        ps += (p0 + p1) + (p2 + p3);
        up[f][jf][0] = __builtin_bit_cast(unsigned, __builtin_amdgcn_cvt_pkrtz(p0, p1));
        up[f][jf][1] = __builtin_bit_cast(unsigned, __builtin_amdgcn_cvt_pkrtz(p2, p3));
      }
      ps += __shfl_xor(ps, 16);
      ps += __shfl_xor(ps, 32);
      lsum[f] += ps;
    }

    // PV: P redistribution (dest lane (G,c) elem e needs P[q=c][j=32kg+8G+e]), V shared across frags
#pragma unroll
    for (int kg = 0; kg < 2; ++kg) {
      half8 pf[2];
#pragma unroll
      for (int f = 0; f < 2; ++f) {
        int f0 = 2 * kg, f1 = f0 + 1;
        int a00 = __shfl((int)up[f][f0][0], la); int a01 = __shfl((int)up[f][f0][1], la);
        int a10 = __shfl((int)up[f][f1][0], la); int a11 = __shfl((int)up[f][f1][1], la);
        int b00 = __shfl((int)up[f][f0][0], lb); int b01 = __shfl((int)up[f][f0][1], lb);
        int b10 = __shfl((int)up[f][f1][0], lb); int b11 = __shfl((int)up[f][f1][1], lb);
        i32x4 pi = { sel_hi ? a10 : a00, sel_hi ? a11 : a01,
                     sel_hi ? b10 : b00, sel_hi ? b11 : b01 };
        pf[f] = __builtin_bit_cast(half8, pi);
      }
      __builtin_amdgcn_s_setprio(1);
#pragma unroll
      for (int df = 0; df < 4; ++df) {
        half8 vf = *reinterpret_cast<const half8*>(
            &Vt[buf][(df * 16 + c) * 64 + (((kg * 4 + G) ^ (c & 7)) << 3)]);
#pragma unroll
        for (int f = 0; f < 2; ++f)
          O[f][df] = __builtin_amdgcn_mfma_f32_16x16x32_f16(vf, pf[f], O[f][df], 0, 0, 0);
      }
      __builtin_amdgcn_s_setprio(0);
    }
    __syncthreads();
  }

  const int bb = bh >> 4, h = bh & 15;
#pragma unroll
  for (int f = 0; f < 2; ++f) {
    float inv = 1.f / lsum[f];
    const size_t srow = (size_t)bb * 2048 + q0 + f * 16 + c;
#pragma unroll
    for (int df = 0; df < 4; ++df) {
      half4 o = { (_Float16)(O[f][df][0] * inv), (_Float16)(O[f][df][1] * inv),
                  (_Float16)(O[f][df][2] * inv), (_Float16)(O[f][df][3] * inv) };
      *reinterpret_cast<half4*>(ao + srow * 1024 + h * 64 + df * 16 + 4 * G) = o;
    }
  }
}

// ---------------- launch ----------------

extern "C" void kernel_launch(void* const* d_in, const int* in_sizes, int n_in,
                              void* d_out, int out_size, void* d_ws, size_t ws_size,
                              hipStream_t stream) {
  const float* x     = (const float*)d_in[0];
  const float* w_qkv = (const float*)d_in[1];
  const float* b_qkv = (const float*)d_in[2];
  const float* w_o   = (const float*)d_in[3];
  const float* b_o   = (const float*)d_in[4];
  float* out = (float*)d_out;
  char* ws = (char*)d_ws;
  _Float16* xh    = (_Float16*)(ws);                       // 8 MB  [4096][1024]
  _Float16* wqkvT = (_Float16*)(ws + ((size_t)8  << 20));  // 6 MB  [3072][1024]
  _Float16* woT   = (_Float16*)(ws + ((size_t)14 << 20));  // 2 MB  [1024][1024]
  _Float16* qh    = (_Float16*)(ws + ((size_t)16 << 20));  // 8 MB  [32][2048][64] (pre-scaled, log2e)
  _Float16* kh    = (_Float16*)(ws + ((size_t)24 << 20));  // 8 MB  [32][2048][64]
  _Float16* vT    = (_Float16*)(ws + ((size_t)32 << 20));  // 8 MB  [32][64][2048]
  _Float16* ao    = (_Float16*)(ws + ((size_t)40 << 20));  // 8 MB  [4096][1024]

  cvt_x_kernel<<<4096, 256, 0, stream>>>(x, xh);
  transpose_cvt_kernel<<<1536, 256, 0, stream>>>(w_qkv, wqkvT, 3072);
  transpose_cvt_kernel<<<512, 256, 0, stream>>>(w_o, woT, 1024);
  gemm16<0><<<dim3(24, 32), 256, 0, stream>>>(xh, wqkvT, b_qkv, qh, kh, vT, nullptr);
  attn_kernel<<<512, 256, 0, stream>>>(qh, kh, vT, ao);
  gemm16<1><<<dim3(8, 32), 256, 0, stream>>>(ao, woT, b_o, nullptr, nullptr, nullptr, out);
}

// Round 3
// 133.738 us; speedup vs baseline: 2.3907x; 1.1869x over previous
//
#include <hip/hip_runtime.h>

typedef __attribute__((ext_vector_type(8))) _Float16 half8;
typedef __attribute__((ext_vector_type(4))) _Float16 half4;
typedef __attribute__((ext_vector_type(4))) float f32x4;
typedef __attribute__((ext_vector_type(16))) float f32x16;
typedef __attribute__((ext_vector_type(4))) int i32x4;

typedef __attribute__((address_space(1))) void* gptr_t;
typedef __attribute__((address_space(3))) void* lptr_t;
#define GLL16(g, l) __builtin_amdgcn_global_load_lds((gptr_t)(g), (lptr_t)(l), 16, 0, 0)

__device__ __forceinline__ float fast_exp2(float x) {
  float r;
  asm volatile("v_exp_f32 %0, %1" : "=v"(r) : "v"(x));
  return r;
}

// ---------------- prep kernels ----------------

__global__ void cvt_x_kernel(const float* __restrict__ x, _Float16* __restrict__ xh) {
  size_t i = (size_t)blockIdx.x * blockDim.x + threadIdx.x;
  float4 v = *reinterpret_cast<const float4*>(x + i * 4);
  half4 o = { (_Float16)v.x, (_Float16)v.y, (_Float16)v.z, (_Float16)v.w };
  *reinterpret_cast<half4*>(xh + i * 4) = o;
}

// w [1024][N] fp32 -> wt [N][1024] fp16 (K-contiguous)
__global__ void transpose_cvt_kernel(const float* __restrict__ w, _Float16* __restrict__ wt, int N) {
  int tid = blockIdx.x * blockDim.x + threadIdx.x;
  int n = tid % N, kc = tid / N;
  half8 o;
#pragma unroll
  for (int i = 0; i < 8; ++i) o[i] = (_Float16)w[(size_t)(kc * 8 + i) * N + n];
  *reinterpret_cast<half8*>(wt + (size_t)n * 1024 + kc * 8) = o;
}

// ---------------- fp16 GEMM, 128x128 tile, BK=64, K=1024 ----------------

template<int EPI>
__global__ __launch_bounds__(256, 2)
void gemm16(const _Float16* __restrict__ A, const _Float16* __restrict__ Bt,
            const float* __restrict__ bias,
            _Float16* __restrict__ qh, _Float16* __restrict__ kh,
            _Float16* __restrict__ vT, float* __restrict__ outf) {
  __shared__ __align__(16) _Float16 Ah[128 * 64];
  __shared__ __align__(16) _Float16 Bh[128 * 64];
  const int t = threadIdx.x;
  const int w = t >> 6, ln = t & 63, G = ln >> 4, c = ln & 15;
  const int m0 = blockIdx.y * 128, n0 = blockIdx.x * 128;
  const int wr = w >> 1, wc = w & 1;
  f32x4 acc[4][4] = {};
  for (int kt = 0; kt < 1024; kt += 64) {
#pragma unroll
    for (int i = 0; i < 4; ++i) {
      int ch = i * 256 + t;
      int row = ch >> 3, kc = ch & 7;
      int kk = kt + ((kc ^ (row & 7)) << 3);
      int ldsbase = (i * 256 + w * 64) * 8;
      GLL16(A + (size_t)(m0 + row) * 1024 + kk, Ah + ldsbase);
      GLL16(Bt + (size_t)(n0 + row) * 1024 + kk, Bh + ldsbase);
    }
    __syncthreads();
    half8 aF[2][4], bF[2][4];
#pragma unroll
    for (int ks = 0; ks < 2; ++ks)
#pragma unroll
      for (int i = 0; i < 4; ++i) {
        int ra = wr * 64 + i * 16 + c;
        aF[ks][i] = *reinterpret_cast<const half8*>(&Ah[ra * 64 + (((ks * 4 + G) ^ (ra & 7)) << 3)]);
        int rb = wc * 64 + i * 16 + c;
        bF[ks][i] = *reinterpret_cast<const half8*>(&Bh[rb * 64 + (((ks * 4 + G) ^ (rb & 7)) << 3)]);
      }
#pragma unroll
    for (int ks = 0; ks < 2; ++ks)
#pragma unroll
      for (int mi = 0; mi < 4; ++mi)
#pragma unroll
        for (int ni = 0; ni < 4; ++ni)
          acc[mi][ni] = __builtin_amdgcn_mfma_f32_16x16x32_f16(aF[ks][mi], bF[ks][ni], acc[mi][ni], 0, 0, 0);
    __syncthreads();
  }
  const int mbase = m0 + wr * 64, nbase = n0 + wc * 64;
  // V pi-permutation: swap bits 2,3 of the within-16 s index (self-inverse) so the
  // attn PV B-frag needs no cross-lane P movement.
  const int Gp = ((G & 1) << 1) | (G >> 1);
#pragma unroll
  for (int ni = 0; ni < 4; ++ni) {
    int n = nbase + ni * 16 + c;
    float bv = bias[n];
    if (EPI == 0) {
      int h = n / 192;
      int rem = n - h * 192;
      int tt = rem >> 6, d = rem & 63;
#pragma unroll
      for (int mi = 0; mi < 4; ++mi) {
        if (tt == 2) {
          int mb = mbase + mi * 16;
          int bb = mb >> 11, s0 = mb & 2047;
          size_t bh = (size_t)(bb * 16 + h);
          half4 o = { (_Float16)(acc[mi][ni][0] + bv), (_Float16)(acc[mi][ni][1] + bv),
                      (_Float16)(acc[mi][ni][2] + bv), (_Float16)(acc[mi][ni][3] + bv) };
          *reinterpret_cast<half4*>(&vT[(bh * 64 + d) * 2048 + s0 + 4 * Gp]) = o;
        } else {
#pragma unroll
          for (int r = 0; r < 4; ++r) {
            int m = mbase + mi * 16 + 4 * G + r;
            int bb = m >> 11, s = m & 2047;
            float val = acc[mi][ni][r] + bv;
            size_t bh = (size_t)(bb * 16 + h);
            // q pre-scaled by hd^-0.5 * log2(e): softmax runs in exp2 domain
            if (tt == 0) qh[(bh * 2048 + s) * 64 + d] = (_Float16)(val * (0.125f * 1.44269504089f));
            else         kh[(bh * 2048 + s) * 64 + d] = (_Float16)val;
          }
        }
      }
    } else {
#pragma unroll
      for (int mi = 0; mi < 4; ++mi)
#pragma unroll
        for (int r = 0; r < 4; ++r) {
          int m = mbase + mi * 16 + 4 * G + r;
          outf[(size_t)m * 1024 + n] = acc[mi][ni][r] + bv;
        }
    }
  }
}

// ---------------- flash attention v3: 32x32 MFMA, in-lane softmax, zero P shuffles ----------------
// Wave owns 32 q-rows. Swapped QK^T (A=K, B=Q) => lane holds P[k 0..31][q=lane&31].
// PV B-frag slots map to st regs IN ORDER because V is pi-permuted in global memory.

__global__ __launch_bounds__(256, 2)
void attn_kernel(const _Float16* __restrict__ qh, const _Float16* __restrict__ kh,
                 const _Float16* __restrict__ vT, _Float16* __restrict__ ao) {
  __shared__ __align__(16) _Float16 Kt[2][64 * 64];
  __shared__ __align__(16) _Float16 Vt[2][64 * 64];
  const int t = threadIdx.x;
  const int w = t >> 6, ln = t & 63, lo = ln & 31, hi = ln >> 5;
  const int bid = blockIdx.x;
  const int xcd = bid & 7, tt = bid >> 3;
  const int bh = xcd * 4 + (tt >> 4);
  const int qb = tt & 15;
  const int q0 = qb * 128 + w * 32;
  const _Float16* qp = qh + (size_t)bh * 2048 * 64;
  const _Float16* kp = kh + (size_t)bh * 2048 * 64;
  const _Float16* vp = vT + (size_t)bh * 64 * 2048;

  half8 qf[4];
#pragma unroll
  for (int sl = 0; sl < 4; ++sl)
    qf[sl] = *reinterpret_cast<const half8*>(qp + (size_t)(q0 + lo) * 64 + sl * 16 + hi * 8);

  f32x16 O0 = {}, O1 = {};
  float mrun = -INFINITY, lsum = 0.f;

  auto stage = [&](int b, int jt) {
#pragma unroll
    for (int i = 0; i < 2; ++i) {
      int ch = i * 256 + t;
      int row = ch >> 3, cc = ch & 7;
      int sw = ((cc ^ (row & 7)) << 3);
      int ldsbase = (i * 256 + w * 64) * 8;
      GLL16(kp + (size_t)(jt + row) * 64 + sw, &Kt[b][ldsbase]);
      GLL16(vp + (size_t)row * 2048 + jt + sw, &Vt[b][ldsbase]);
    }
  };

  stage(0, 0);
  __syncthreads();

  for (int it = 0; it < 32; ++it) {
    const int buf = it & 1;
    if (it < 31) stage(buf ^ 1, (it + 1) * 64);

    f32x16 st0 = {}, st1 = {};
    __builtin_amdgcn_s_setprio(1);
#pragma unroll
    for (int sl = 0; sl < 4; ++sl) {
      const int ch = sl * 2 + hi;
      half8 k0 = *reinterpret_cast<const half8*>(&Kt[buf][lo * 64 + ((ch ^ (lo & 7)) << 3)]);
      half8 k1 = *reinterpret_cast<const half8*>(&Kt[buf][(32 + lo) * 64 + ((ch ^ ((32 + lo) & 7)) << 3)]);
      st0 = __builtin_amdgcn_mfma_f32_32x32x16_f16(k0, qf[sl], st0, 0, 0, 0);
      st1 = __builtin_amdgcn_mfma_f32_32x32x16_f16(k1, qf[sl], st1, 0, 0, 0);
    }
    __builtin_amdgcn_s_setprio(0);

    // in-lane max over 32 keys (all for q = q0+lo), then combine lane pairs l, l+32
    float mx[8];
#pragma unroll
    for (int i = 0; i < 8; ++i) mx[i] = fmaxf(fmaxf(st0[i], st0[i + 8]), fmaxf(st1[i], st1[i + 8]));
#pragma unroll
    for (int i = 0; i < 4; ++i) mx[i] = fmaxf(mx[i], mx[i + 4]);
    float tm = fmaxf(fmaxf(mx[0], mx[1]), fmaxf(mx[2], mx[3]));
    tm = fmaxf(tm, __shfl_xor(tm, 32));
    if (!__all(tm <= mrun + 8.f)) {
      float mnew = fmaxf(mrun, tm);
      float corr = fast_exp2(mrun - mnew);
      lsum *= corr;
#pragma unroll
      for (int i = 0; i < 16; ++i) { O0[i] *= corr; O1[i] *= corr; }
      mrun = mnew;
    }
#pragma unroll
    for (int i = 0; i < 16; ++i) st0[i] = fast_exp2(st0[i] - mrun);
#pragma unroll
    for (int i = 0; i < 16; ++i) st1[i] = fast_exp2(st1[i] - mrun);
    float sm[8];
#pragma unroll
    for (int i = 0; i < 8; ++i) sm[i] = (st0[i] + st0[i + 8]) + (st1[i] + st1[i + 8]);
#pragma unroll
    for (int i = 0; i < 4; ++i) sm[i] += sm[i + 4];
    float ps = (sm[0] + sm[1]) + (sm[2] + sm[3]);
    ps += __shfl_xor(ps, 32);
    lsum += ps;

    // pack P: pf[kb2] = st regs in order (pi-permutation baked into V layout)
    unsigned pk[4][4];
#pragma unroll
    for (int kh2 = 0; kh2 < 2; ++kh2)
#pragma unroll
      for (int j = 0; j < 4; ++j) {
        pk[kh2][j]     = __builtin_bit_cast(unsigned, __builtin_amdgcn_cvt_pkrtz(st0[kh2 * 8 + 2 * j], st0[kh2 * 8 + 2 * j + 1]));
        pk[2 + kh2][j] = __builtin_bit_cast(unsigned, __builtin_amdgcn_cvt_pkrtz(st1[kh2 * 8 + 2 * j], st1[kh2 * 8 + 2 * j + 1]));
      }

    __builtin_amdgcn_s_setprio(1);
#pragma unroll
    for (int kb2 = 0; kb2 < 4; ++kb2) {
      i32x4 pi = { (int)pk[kb2][0], (int)pk[kb2][1], (int)pk[kb2][2], (int)pk[kb2][3] };
      half8 pf = __builtin_bit_cast(half8, pi);
      const int ch = kb2 * 2 + hi;
      half8 v0 = *reinterpret_cast<const half8*>(&Vt[buf][lo * 64 + ((ch ^ (lo & 7)) << 3)]);
      half8 v1 = *reinterpret_cast<const half8*>(&Vt[buf][(32 + lo) * 64 + ((ch ^ ((32 + lo) & 7)) << 3)]);
      O0 = __builtin_amdgcn_mfma_f32_32x32x16_f16(v0, pf, O0, 0, 0, 0);
      O1 = __builtin_amdgcn_mfma_f32_32x32x16_f16(v1, pf, O1, 0, 0, 0);
    }
    __builtin_amdgcn_s_setprio(0);
    __syncthreads();
  }

  // epilogue: O[vb][reg] = O_mat[d = vb*32 + (reg&3) + 8*(reg>>2) + 4*hi][q = lo]
  float inv = 1.f / lsum;
  const int bb = bh >> 4, h = bh & 15;
  const size_t srow = (size_t)bb * 2048 + q0 + lo;
  _Float16* aob = ao + srow * 1024 + h * 64 + hi * 4;
#pragma unroll
  for (int rq = 0; rq < 4; ++rq) {
    half4 o0 = { (_Float16)(O0[4 * rq] * inv), (_Float16)(O0[4 * rq + 1] * inv),
                 (_Float16)(O0[4 * rq + 2] * inv), (_Float16)(O0[4 * rq + 3] * inv) };
    *reinterpret_cast<half4*>(aob + rq * 8) = o0;
    half4 o1 = { (_Float16)(O1[4 * rq] * inv), (_Float16)(O1[4 * rq + 1] * inv),
                 (_Float16)(O1[4 * rq + 2] * inv), (_Float16)(O1[4 * rq + 3] * inv) };
    *reinterpret_cast<half4*>(aob + 32 + rq * 8) = o1;
  }
}

// ---------------- launch ----------------

extern "C" void kernel_launch(void* const* d_in, const int* in_sizes, int n_in,
                              void* d_out, int out_size, void* d_ws, size_t ws_size,
                              hipStream_t stream) {
  const float* x     = (const float*)d_in[0];
  const float* w_qkv = (const float*)d_in[1];
  const float* b_qkv = (const float*)d_in[2];
  const float* w_o   = (const float*)d_in[3];
  const float* b_o   = (const float*)d_in[4];
  float* out = (float*)d_out;
  char* ws = (char*)d_ws;
  _Float16* xh    = (_Float16*)(ws);                       // 8 MB  [4096][1024]
  _Float16* wqkvT = (_Float16*)(ws + ((size_t)8  << 20));  // 6 MB  [3072][1024]
  _Float16* woT   = (_Float16*)(ws + ((size_t)14 << 20));  // 2 MB  [1024][1024]
  _Float16* qh    = (_Float16*)(ws + ((size_t)16 << 20));  // 8 MB  [32][2048][64] (pre-scaled, log2e)
  _Float16* kh    = (_Float16*)(ws + ((size_t)24 << 20));  // 8 MB  [32][2048][64]
  _Float16* vT    = (_Float16*)(ws + ((size_t)32 << 20));  // 8 MB  [32][64][2048] (pi-permuted s within 16)
  _Float16* ao    = (_Float16*)(ws + ((size_t)40 << 20));  // 8 MB  [4096][1024]

  cvt_x_kernel<<<4096, 256, 0, stream>>>(x, xh);
  transpose_cvt_kernel<<<1536, 256, 0, stream>>>(w_qkv, wqkvT, 3072);
  transpose_cvt_kernel<<<512, 256, 0, stream>>>(w_o, woT, 1024);
  gemm16<0><<<dim3(24, 32), 256, 0, stream>>>(xh, wqkvT, b_qkv, qh, kh, vT, nullptr);
  attn_kernel<<<512, 256, 0, stream>>>(qh, kh, vT, ao);
  gemm16<1><<<dim3(8, 32), 256, 0, stream>>>(ao, woT, b_o, nullptr, nullptr, nullptr, out);
}